// Round 13
// baseline (95.735 us; speedup 1.0000x reference)
//
#include <hip/hip_runtime.h>
#include <hip/hip_bf16.h>

// Problem constants
#define BATCH 2
#define SEQ   2048
#define EMBD  1024
#define NHEAD 16
#define HDIM  64
#define N3    3072           // 3*EMBD
#define MTOT  4096           // BATCH*SEQ
#define KDIM  1024

typedef __attribute__((ext_vector_type(8))) short  short8;   // 8 x bf16 (4 VGPRs)
typedef __attribute__((ext_vector_type(4))) short  s16x4;
typedef __attribute__((ext_vector_type(4))) float  f32x4;

__device__ __forceinline__ short f2bfs(float f) {
    return __builtin_bit_cast(short, __float2bfloat16(f));   // compiler emits v_cvt_pk_bf16_f32 for pairs
}

// ---------------------------------------------------------------- cast x -> bf16
__global__ __launch_bounds__(256) void cast_x_kernel(const float* __restrict__ x,
                                                     short* __restrict__ xb, int n4) {
    int i = blockIdx.x * 256 + threadIdx.x;
    if (i >= n4) return;
    float4 f = reinterpret_cast<const float4*>(x)[i];
    s16x4 o;
    o[0] = f2bfs(f.x); o[1] = f2bfs(f.y);
    o[2] = f2bfs(f.z); o[3] = f2bfs(f.w);
    reinterpret_cast<s16x4*>(xb)[i] = o;
}

// ------------------------------------------- cast + transpose w [K,N3] -> wt [N3,K]
__global__ __launch_bounds__(256) void cast_wt_kernel(const float* __restrict__ w,
                                                      short* __restrict__ wt) {
    __shared__ float tile[32][33];
    int n0 = blockIdx.x * 32;   // N3/32 = 96
    int k0 = blockIdx.y * 32;   // K/32  = 32
    int tx = threadIdx.x & 31;
    int ty = threadIdx.x >> 5;  // 0..7
#pragma unroll
    for (int i = 0; i < 4; ++i)
        tile[ty + i * 8][tx] = w[(size_t)(k0 + ty + i * 8) * N3 + n0 + tx];
    __syncthreads();
#pragma unroll
    for (int i = 0; i < 4; ++i)
        wt[(size_t)(n0 + ty + i * 8) * KDIM + k0 + tx] = f2bfs(tile[tx][ty + i * 8]);
}

// ---------------------------------------------------------------- QKV GEMM
// C[m,n] = sum_k xb[m,k] * wt[n,k];  M=4096, N=3072, K=1024
__device__ __forceinline__ void stage_tile(const short* gbase, short* lbase, int tid) {
#pragma unroll
    for (int c = 0; c < 2; ++c) {
        int row = c * 64 + (tid >> 2);
        int chunk = (tid & 3) ^ ((row >> 1) & 3);    // inverse-swizzled source
        const short* gp = gbase + (size_t)row * KDIM + chunk * 8;
        short* lp = lbase + c * 2048 + tid * 8;      // linear dest: row, slot tid&3
        __builtin_amdgcn_global_load_lds((const __attribute__((address_space(1))) void*)gp,
                                         (__attribute__((address_space(3))) void*)lp,
                                         16, 0, 0);
    }
}

__global__ __launch_bounds__(256) void qkv_gemm_kernel(const short* __restrict__ xb,
                                                       const short* __restrict__ wt,
                                                       short* __restrict__ qb,
                                                       short* __restrict__ kbuf,
                                                       short* __restrict__ vt) {
    __shared__ short lA[2][128 * 32];
    __shared__ short lB[2][128 * 32];

    const int tid  = threadIdx.x;
    const int lane = tid & 63;
    const int wid  = tid >> 6;
    const int wm = wid >> 1, wn = wid & 1;
    // XCD-aware bijective swizzle (768 = 8 XCDs x 96): each XCD owns 4 m-rows
    const int lid = blockIdx.x;
    const int swz = (lid & 7) * 96 + (lid >> 3);
    const int m0 = (swz / 24) * 128;
    const int n0 = (swz % 24) * 128;

    f32x4 acc[4][4];
#pragma unroll
    for (int i = 0; i < 4; ++i)
#pragma unroll
        for (int j = 0; j < 4; ++j) acc[i][j] = (f32x4){0.f, 0.f, 0.f, 0.f};

    const short* gA = xb + (size_t)m0 * KDIM;
    const short* gB = wt + (size_t)n0 * KDIM;

    stage_tile(gA, lA[0], tid);
    stage_tile(gB, lB[0], tid);

    int cur = 0;
    // swizzled fragment slot: hi ^ ((row>>1)&3), row bits from lane&15
    const int arow = (lane & 15) * 32 + (((lane >> 4) ^ ((lane >> 1) & 3)) * 8);
#pragma unroll 1
    for (int kt = 0; kt < KDIM / 32; ++kt) {
        if (kt + 1 < KDIM / 32) {
            stage_tile(gA + (kt + 1) * 32, lA[cur ^ 1], tid);
            stage_tile(gB + (kt + 1) * 32, lB[cur ^ 1], tid);
            asm volatile("s_waitcnt vmcnt(4)" ::: "memory");   // kt resident; kt+1 in flight
        } else {
            asm volatile("s_waitcnt vmcnt(0)" ::: "memory");
        }
        __builtin_amdgcn_s_barrier();
        __builtin_amdgcn_sched_barrier(0);
        short8 a[4], b[4];
#pragma unroll
        for (int im = 0; im < 4; ++im)
            a[im] = *(const short8*)&lA[cur][(wm * 64 + im * 16) * 32 + arow];
#pragma unroll
        for (int in = 0; in < 4; ++in)
            b[in] = *(const short8*)&lB[cur][(wn * 64 + in * 16) * 32 + arow];
#pragma unroll
        for (int im = 0; im < 4; ++im)
#pragma unroll
            for (int in = 0; in < 4; ++in)
                acc[im][in] = __builtin_amdgcn_mfma_f32_16x16x32_bf16(a[im], b[in], acc[im][in], 0, 0, 0);
        __builtin_amdgcn_sched_barrier(0);
        __builtin_amdgcn_s_barrier();                          // WAR: reads done before next stage
        cur ^= 1;
    }

    // epilogue: scatter to q*0.125 [B,H,T,D], k [B,H,T,D], v^T [B,H,D,T]
#pragma unroll
    for (int im = 0; im < 4; ++im) {
        int t0m = m0 + wm * 64 + im * 16 + (lane >> 4) * 4;
        int b = t0m >> 11;
        int t0 = t0m & 2047;
#pragma unroll
        for (int in = 0; in < 4; ++in) {
            int col = n0 + wn * 64 + in * 16 + (lane & 15);
            int which = col >> 10;
            int h = (col >> 6) & 15;
            int d = col & 63;
            if (which == 2) {
                s16x4 pk;
#pragma unroll
                for (int r = 0; r < 4; ++r) pk[r] = f2bfs(acc[im][in][r]);
                *(s16x4*)&vt[((size_t)(b * NHEAD + h) * HDIM + d) * SEQ + t0] = pk;
            } else {
                short* dst = (which == 0) ? qb : kbuf;
                float sc = (which == 0) ? 0.125f : 1.0f;   // fold 1/sqrt(D) into Q (exact pow2)
#pragma unroll
                for (int r = 0; r < 4; ++r)
                    dst[((size_t)(b * NHEAD + h) * SEQ + t0 + r) * HDIM + d] = f2bfs(acc[im][in][r] * sc);
            }
        }
    }
}

// ---------------------------------------------------------------- flash attention
// 512 blocks x 512 threads (8 waves, 128 q-rows each): each 32KB K/V stage now
// serves 8 waves (was 4) -> staged bytes halve (the R12 TA/L1-path limiter).
// Static LPT pairing per CU: q-tiles {15-ps, ps} -> (2(15-ps)+2)+(2ps+2)=34
// kv-iterations per CU, constant; long half dispatched first; heads XCD-pinned.
// Per-wave code identical to R12 (swapped QK^T, P-in-registers, defer-max).
#define KVB 64

__device__ __forceinline__ int swzf(int r) { return (r & 3) ^ (((r >> 2) & 3) << 1); }

__device__ __forceinline__ void stage_kv(const short* kh, const short* vh, int kb,
                                         short* lk, short* lv, int tid) {
    int row = tid >> 3;                              // 0..63
    int sch = (tid & 7) ^ swzf(row);                 // swizzled 16B-chunk index
    const short* gk = kh + (size_t)(kb + row) * HDIM + sch * 8;
    __builtin_amdgcn_global_load_lds((const __attribute__((address_space(1))) void*)gk,
                                     (__attribute__((address_space(3))) void*)(lk + tid * 8), 16, 0, 0);
    const short* gv = vh + (size_t)row * SEQ + kb + sch * 8;   // row = d index
    __builtin_amdgcn_global_load_lds((const __attribute__((address_space(1))) void*)gv,
                                     (__attribute__((address_space(3))) void*)(lv + tid * 8), 16, 0, 0);
}

struct AttnState {
    f32x4 o[4];
    float mrun, lrun;
};

__device__ __forceinline__ void compute_tile(const short* lk, const short* lv, int kb,
                                             int qbase, int qrow, int rbase, int hi,
                                             const short8* aQ, const short8& vone,
                                             AttnState& st) {
    const float L2E = 1.4426950408889634f;
    // ---- QK^T swapped: s[nb] = S^T block; lane col = my q-row.
    f32x4 s[4];
    __builtin_amdgcn_s_setprio(1);
#pragma unroll
    for (int nb = 0; nb < 4; ++nb) {
        int kidx = (nb & 1) * 32 + (rbase >> 2) * 8 + (nb >> 1) * 4 + (rbase & 3);
        f32x4 a = (f32x4){0.f, 0.f, 0.f, 0.f};
#pragma unroll
        for (int c = 0; c < 2; ++c) {
            int slot2 = (c * 4 + hi) ^ swzf(kidx);
            short8 bK = *(const short8*)&lk[kidx * 64 + slot2 * 8];
            a = __builtin_amdgcn_mfma_f32_16x16x32_bf16(bK, aQ[c], a, 0, 0, 0);
        }
        s[nb] = a;
    }
    __builtin_amdgcn_s_setprio(0);
    // ---- causal mask (diagonal tile only; wave-uniform branch)
    if (kb + KVB - 1 > qbase) {
#pragma unroll
        for (int nb = 0; nb < 4; ++nb) {
            int keyb = kb + (nb & 1) * 32 + hi * 8 + (nb >> 1) * 4;
#pragma unroll
            for (int r = 0; r < 4; ++r)
                if (keyb + r > qrow) s[nb][r] = -1e30f;
        }
    }
    // ---- row max: max3-friendly nesting + 2 shfl across hi-groups
    float pm = fmaxf(fmaxf(fmaxf(fmaxf(s[0][0], s[0][1]), s[0][2]),
                           fmaxf(fmaxf(s[0][3], s[1][0]), s[1][1])),
                     fmaxf(fmaxf(fmaxf(s[1][2], s[1][3]), s[2][0]),
                           fmaxf(fmaxf(s[2][1], s[2][2]), s[2][3])));
    pm = fmaxf(fmaxf(pm, s[3][0]), fmaxf(fmaxf(s[3][1], s[3][2]), s[3][3]));
    pm = fmaxf(pm, __shfl_xor(pm, 16));
    pm = fmaxf(pm, __shfl_xor(pm, 32));
    // ---- defer-max (T13, THR=8): rescale only on growth beyond headroom
    if (__any(pm > st.mrun + 8.0f)) {
        float mnew = fmaxf(st.mrun, pm);
        float sf = exp2f((st.mrun - mnew) * L2E);
        st.mrun = mnew;
        st.lrun *= sf;
#pragma unroll
        for (int dt = 0; dt < 4; ++dt)
#pragma unroll
            for (int r = 0; r < 4; ++r) st.o[dt][r] *= sf;
    }
    float mterm = st.mrun * L2E;
    // ---- P = exp2(s*L2E - mterm) -> bf16 (packed cvt), as PV B-frags
    short8 bp[2];
#pragma unroll
    for (int c = 0; c < 2; ++c)
#pragma unroll
        for (int jj = 0; jj < 8; ++jj) {
            float p = exp2f(fmaf(s[c + (jj >> 2) * 2][jj & 3], L2E, -mterm));
            bp[c][jj] = f2bfs(p);
        }
    // ---- PV swapped: o^T[d][qrow] += V^T-frag * P^T-frag; + ones row-sum
    f32x4 osum = (f32x4){0.f, 0.f, 0.f, 0.f};
    __builtin_amdgcn_s_setprio(1);
#pragma unroll
    for (int dt = 0; dt < 4; ++dt) {
        int d = dt * 16 + rbase;
#pragma unroll
        for (int c = 0; c < 2; ++c) {
            int slot2 = (c * 4 + hi) ^ swzf(d);
            short8 bV = *(const short8*)&lv[d * 64 + slot2 * 8];
            st.o[dt] = __builtin_amdgcn_mfma_f32_16x16x32_bf16(bV, bp[c], st.o[dt], 0, 0, 0);
        }
    }
#pragma unroll
    for (int c = 0; c < 2; ++c)
        osum = __builtin_amdgcn_mfma_f32_16x16x32_bf16(vone, bp[c], osum, 0, 0, 0);
    __builtin_amdgcn_s_setprio(0);
    st.lrun += osum[0];
}

__global__ __launch_bounds__(512) void attn_kernel(const short* __restrict__ q,
                                                   const short* __restrict__ kk,
                                                   const short* __restrict__ vtg,
                                                   float* __restrict__ out) {
    const int tid  = threadIdx.x;
    const int lane = tid & 63;
    const int wid  = tid >> 6;                       // 0..7
    const int lid  = blockIdx.x;                     // 0..511
    const int xcd  = lid & 7;
    const int v    = lid >> 3;                       // 0..63
    const int h4   = v & 3;                          // head rank on this XCD
    const int ps   = (v >> 2) & 7;                   // CU pair-slot
    const int half = v >> 5;                         // 0 = long half (first)
    const int qt   = half ? ps : (15 - ps);          // q-tile of 128 rows
    const int bh   = h4 * 8 + xcd;                   // pinned to XCD
    const int rbase = lane & 15;                     // my q-row within wave tile
    const int hi    = lane >> 4;

    const short* qh = q   + (size_t)bh * SEQ * HDIM;
    const short* kh = kk  + (size_t)bh * SEQ * HDIM;
    const short* vh = vtg + (size_t)bh * HDIM * SEQ;

    __shared__ short lK[2][KVB * 64];
    __shared__ short lV[2][KVB * 64];

    short8 vone;
#pragma unroll
    for (int jj = 0; jj < 8; ++jj) vone[jj] = (short)0x3F80;   // bf16 1.0

    const int b = bh >> 4, h = bh & 15;

    const int qbase = qt * 128 + wid * 16;
    const int qrow  = qbase + rbase;

    // Q fragment (B-frag: lane n=rbase holds Q[qrow][k], k = hi*8+j)
    short8 aQ[2];
#pragma unroll
    for (int c = 0; c < 2; ++c)
        aQ[c] = *(const short8*)&qh[(size_t)qrow * HDIM + c * 32 + hi * 8];

    AttnState st;
#pragma unroll
    for (int i = 0; i < 4; ++i) st.o[i] = (f32x4){0.f, 0.f, 0.f, 0.f};
    st.mrun = -INFINITY;
    st.lrun = 0.f;

    const int ktiles = 2 * qt + 2;                   // rows qt*128..qt*128+127
    stage_kv(kh, vh, 0, lK[0], lV[0], tid);
#pragma unroll 1
    for (int t = 0; t < ktiles; t += 2) {
        {   // ---- even tile: compute lK[0]/lV[0], stage t+1 -> buf1
            const int kb = t * KVB;
            if (t + 1 < ktiles) {
                stage_kv(kh, vh, kb + KVB, lK[1], lV[1], tid);
                asm volatile("s_waitcnt vmcnt(2)" ::: "memory");
            } else {
                asm volatile("s_waitcnt vmcnt(0)" ::: "memory");
            }
            __builtin_amdgcn_s_barrier();
            __builtin_amdgcn_sched_barrier(0);
            if (kb < qbase + 16)
                compute_tile(lK[0], lV[0], kb, qbase, qrow, rbase, hi, aQ, vone, st);
            __builtin_amdgcn_sched_barrier(0);
            __builtin_amdgcn_s_barrier();
        }
        if (t + 1 < ktiles) {   // ---- odd tile: compute lK[1]/lV[1], stage t+2 -> buf0
            const int kb = (t + 1) * KVB;
            if (t + 2 < ktiles) {
                stage_kv(kh, vh, kb + KVB, lK[0], lV[0], tid);
                asm volatile("s_waitcnt vmcnt(2)" ::: "memory");
            } else {
                asm volatile("s_waitcnt vmcnt(0)" ::: "memory");
            }
            __builtin_amdgcn_s_barrier();
            __builtin_amdgcn_sched_barrier(0);
            if (kb < qbase + 16)
                compute_tile(lK[1], lV[1], kb, qbase, qrow, rbase, hi, aQ, vone, st);
            __builtin_amdgcn_sched_barrier(0);
            __builtin_amdgcn_s_barrier();
        }
    }

    // write out [B,T,H,D] fp32: lane owns row qrow, d = dt*16 + hi*4 + r
    float inv = 1.0f / st.lrun;
#pragma unroll
    for (int dt = 0; dt < 4; ++dt) {
        f32x4 ov;
#pragma unroll
        for (int r = 0; r < 4; ++r) ov[r] = st.o[dt][r] * inv;
        *(f32x4*)&out[((size_t)(b * SEQ + qrow) * NHEAD + h) * HDIM + dt * 16 + hi * 4] = ov;
    }
}

// ---------------------------------------------------------------- launch
extern "C" void kernel_launch(void* const* d_in, const int* in_sizes, int n_in,
                              void* d_out, int out_size, void* d_ws, size_t ws_size,
                              hipStream_t stream) {
    const float* x = (const float*)d_in[0];
    const float* w = (const float*)d_in[1];
    float* out = (float*)d_out;

    char* ws = (char*)d_ws;
    short* xb   = (short*)(ws);                            // 8 MB  [M,K] bf16
    short* wt   = (short*)(ws + (size_t)8  * 1024 * 1024); // 6 MB  [N3,K] bf16
    short* qb   = (short*)(ws + (size_t)14 * 1024 * 1024); // 8 MB  [B,H,T,D] (pre-scaled 0.125)
    short* kbuf = (short*)(ws + (size_t)22 * 1024 * 1024); // 8 MB  [B,H,T,D]
    short* vt   = (short*)(ws + (size_t)30 * 1024 * 1024); // 8 MB  [B,H,D,T]

    cast_x_kernel<<<dim3(MTOT * KDIM / 4 / 256), dim3(256), 0, stream>>>(x, xb, MTOT * KDIM / 4);
    cast_wt_kernel<<<dim3(N3 / 32, KDIM / 32), dim3(256), 0, stream>>>(w, wt);
    qkv_gemm_kernel<<<dim3(768), dim3(256), 0, stream>>>(xb, wt, qb, kbuf, vt);
    attn_kernel<<<dim3(512), dim3(512), 0, stream>>>(qb, kbuf, vt, out);
}

// Round 14
// 90.402 us; speedup vs baseline: 1.0590x; 1.0590x over previous
//
#include <hip/hip_runtime.h>
#include <hip/hip_bf16.h>

// Problem constants
#define BATCH 2
#define SEQ   2048
#define EMBD  1024
#define NHEAD 16
#define HDIM  64
#define N3    3072           // 3*EMBD
#define MTOT  4096           // BATCH*SEQ
#define KDIM  1024

typedef __attribute__((ext_vector_type(8))) short  short8;   // 8 x bf16 (4 VGPRs)
typedef __attribute__((ext_vector_type(4))) short  s16x4;
typedef __attribute__((ext_vector_type(4))) float  f32x4;

__device__ __forceinline__ short f2bfs(float f) {
    return __builtin_bit_cast(short, __float2bfloat16(f));   // compiler emits v_cvt_pk_bf16_f32 for pairs
}

// ---------------------------------------------------------------- cast x -> bf16
__global__ __launch_bounds__(256) void cast_x_kernel(const float* __restrict__ x,
                                                     short* __restrict__ xb, int n4) {
    int i = blockIdx.x * 256 + threadIdx.x;
    if (i >= n4) return;
    float4 f = reinterpret_cast<const float4*>(x)[i];
    s16x4 o;
    o[0] = f2bfs(f.x); o[1] = f2bfs(f.y);
    o[2] = f2bfs(f.z); o[3] = f2bfs(f.w);
    reinterpret_cast<s16x4*>(xb)[i] = o;
}

// ------------------------------------------- cast + transpose w [K,N3] -> wt [N3,K]
__global__ __launch_bounds__(256) void cast_wt_kernel(const float* __restrict__ w,
                                                      short* __restrict__ wt) {
    __shared__ float tile[32][33];
    int n0 = blockIdx.x * 32;   // N3/32 = 96
    int k0 = blockIdx.y * 32;   // K/32  = 32
    int tx = threadIdx.x & 31;
    int ty = threadIdx.x >> 5;  // 0..7
#pragma unroll
    for (int i = 0; i < 4; ++i)
        tile[ty + i * 8][tx] = w[(size_t)(k0 + ty + i * 8) * N3 + n0 + tx];
    __syncthreads();
#pragma unroll
    for (int i = 0; i < 4; ++i)
        wt[(size_t)(n0 + ty + i * 8) * KDIM + k0 + tx] = f2bfs(tile[tx][ty + i * 8]);
}

// ---------------------------------------------------------------- QKV GEMM
// C[m,n] = sum_k xb[m,k] * wt[n,k];  M=4096, N=3072, K=1024
__device__ __forceinline__ void stage_tile(const short* gbase, short* lbase, int tid) {
#pragma unroll
    for (int c = 0; c < 2; ++c) {
        int row = c * 64 + (tid >> 2);
        int chunk = (tid & 3) ^ ((row >> 1) & 3);    // inverse-swizzled source
        const short* gp = gbase + (size_t)row * KDIM + chunk * 8;
        short* lp = lbase + c * 2048 + tid * 8;      // linear dest: row, slot tid&3
        __builtin_amdgcn_global_load_lds((const __attribute__((address_space(1))) void*)gp,
                                         (__attribute__((address_space(3))) void*)lp,
                                         16, 0, 0);
    }
}

__global__ __launch_bounds__(256) void qkv_gemm_kernel(const short* __restrict__ xb,
                                                       const short* __restrict__ wt,
                                                       short* __restrict__ qb,
                                                       short* __restrict__ kbuf,
                                                       short* __restrict__ vt) {
    __shared__ short lA[2][128 * 32];
    __shared__ short lB[2][128 * 32];

    const int tid  = threadIdx.x;
    const int lane = tid & 63;
    const int wid  = tid >> 6;
    const int wm = wid >> 1, wn = wid & 1;
    // XCD-aware bijective swizzle (768 = 8 XCDs x 96): each XCD owns 4 m-rows
    const int lid = blockIdx.x;
    const int swz = (lid & 7) * 96 + (lid >> 3);
    const int m0 = (swz / 24) * 128;
    const int n0 = (swz % 24) * 128;

    f32x4 acc[4][4];
#pragma unroll
    for (int i = 0; i < 4; ++i)
#pragma unroll
        for (int j = 0; j < 4; ++j) acc[i][j] = (f32x4){0.f, 0.f, 0.f, 0.f};

    const short* gA = xb + (size_t)m0 * KDIM;
    const short* gB = wt + (size_t)n0 * KDIM;

    stage_tile(gA, lA[0], tid);
    stage_tile(gB, lB[0], tid);

    int cur = 0;
    // swizzled fragment slot: hi ^ ((row>>1)&3), row bits from lane&15
    const int arow = (lane & 15) * 32 + (((lane >> 4) ^ ((lane >> 1) & 3)) * 8);
#pragma unroll 1
    for (int kt = 0; kt < KDIM / 32; ++kt) {
        if (kt + 1 < KDIM / 32) {
            stage_tile(gA + (kt + 1) * 32, lA[cur ^ 1], tid);
            stage_tile(gB + (kt + 1) * 32, lB[cur ^ 1], tid);
            asm volatile("s_waitcnt vmcnt(4)" ::: "memory");   // kt resident; kt+1 in flight
        } else {
            asm volatile("s_waitcnt vmcnt(0)" ::: "memory");
        }
        __builtin_amdgcn_s_barrier();
        __builtin_amdgcn_sched_barrier(0);
        short8 a[4], b[4];
#pragma unroll
        for (int im = 0; im < 4; ++im)
            a[im] = *(const short8*)&lA[cur][(wm * 64 + im * 16) * 32 + arow];
#pragma unroll
        for (int in = 0; in < 4; ++in)
            b[in] = *(const short8*)&lB[cur][(wn * 64 + in * 16) * 32 + arow];
#pragma unroll
        for (int im = 0; im < 4; ++im)
#pragma unroll
            for (int in = 0; in < 4; ++in)
                acc[im][in] = __builtin_amdgcn_mfma_f32_16x16x32_bf16(a[im], b[in], acc[im][in], 0, 0, 0);
        __builtin_amdgcn_sched_barrier(0);
        __builtin_amdgcn_s_barrier();                          // WAR: reads done before next stage
        cur ^= 1;
    }

    // epilogue: scatter to q*0.125 [B,H,T,D], k [B,H,T,D], v^T [B,H,D,T]
#pragma unroll
    for (int im = 0; im < 4; ++im) {
        int t0m = m0 + wm * 64 + im * 16 + (lane >> 4) * 4;
        int b = t0m >> 11;
        int t0 = t0m & 2047;
#pragma unroll
        for (int in = 0; in < 4; ++in) {
            int col = n0 + wn * 64 + in * 16 + (lane & 15);
            int which = col >> 10;
            int h = (col >> 6) & 15;
            int d = col & 63;
            if (which == 2) {
                s16x4 pk;
#pragma unroll
                for (int r = 0; r < 4; ++r) pk[r] = f2bfs(acc[im][in][r]);
                *(s16x4*)&vt[((size_t)(b * NHEAD + h) * HDIM + d) * SEQ + t0] = pk;
            } else {
                short* dst = (which == 0) ? qb : kbuf;
                float sc = (which == 0) ? 0.125f : 1.0f;   // fold 1/sqrt(D) into Q (exact pow2)
#pragma unroll
                for (int r = 0; r < 4; ++r)
                    dst[((size_t)(b * NHEAD + h) * SEQ + t0 + r) * HDIM + d] = f2bfs(acc[im][in][r] * sc);
            }
        }
    }
}

// ---------------------------------------------------------------- flash attention
// KVB=128: per-tile fixed overhead (stage addressing, 2 barriers, max-reduce,
// defer-max, loop machinery) amortized over 2x keys; long-block iterations 32->16.
// 512 blocks x 512 threads (8 waves, 128 q-rows); 2 blocks/CU (64KB LDS each).
// Static LPT pairing per CU: q-tiles {15-ps, ps}; heads XCD-pinned (bh%8==xcd).
// SWAPPED QK^T with permuted K rows: key(nb,m)=(nb&3)*32+(m>>2)*8+(nb>>2)*4+(m&3)
// -> lane-local P values are exactly the PV B-frags (bp[c][j]=s[c+(j>>2)*4][j&3]).
#define KVB 128

__device__ __forceinline__ int swzf(int r) { return (r & 3) ^ (((r >> 2) & 3) << 1); }

// K: [128 rows][8 chunks of 16B], chunk slot ^ swzf(row).
// V: [64 d-rows][16 chunks of 16B], chunk slot ^ (d&7).
__device__ __forceinline__ void stage_kv(const short* kh, const short* vh, int kb,
                                         short* lk, short* lv, int tid) {
#pragma unroll
    for (int c = 0; c < 2; ++c) {
        int row = c * 64 + (tid >> 3);               // 0..127
        int sch = (tid & 7) ^ swzf(row);
        const short* gk = kh + (size_t)(kb + row) * HDIM + sch * 8;
        __builtin_amdgcn_global_load_lds((const __attribute__((address_space(1))) void*)gk,
                                         (__attribute__((address_space(3))) void*)(lk + c * 4096 + tid * 8), 16, 0, 0);
    }
#pragma unroll
    for (int c = 0; c < 2; ++c) {
        int d = c * 32 + (tid >> 4);                 // 0..63
        int sch = (tid & 15) ^ (d & 7);
        const short* gv = vh + (size_t)d * SEQ + kb + sch * 8;
        __builtin_amdgcn_global_load_lds((const __attribute__((address_space(1))) void*)gv,
                                         (__attribute__((address_space(3))) void*)(lv + c * 4096 + tid * 8), 16, 0, 0);
    }
}

struct AttnState {
    f32x4 o[4];
    float mrun, lrun;
};

__device__ __forceinline__ void compute_tile(const short* lk, const short* lv, int kb,
                                             int qbase, int qrow, int rbase, int hi,
                                             const short8* aQ, const short8& vone,
                                             AttnState& st) {
    const float L2E = 1.4426950408889634f;
    // ---- QK^T swapped: 8 score-blocks of 16 keys; lane col = my q-row.
    f32x4 s[8];
    __builtin_amdgcn_s_setprio(1);
#pragma unroll
    for (int nb = 0; nb < 8; ++nb) {
        int kidx = (nb & 3) * 32 + (rbase >> 2) * 8 + (nb >> 2) * 4 + (rbase & 3);
        f32x4 a = (f32x4){0.f, 0.f, 0.f, 0.f};
#pragma unroll
        for (int c = 0; c < 2; ++c) {
            int slot2 = (c * 4 + hi) ^ swzf(kidx);
            short8 bK = *(const short8*)&lk[kidx * 64 + slot2 * 8];
            a = __builtin_amdgcn_mfma_f32_16x16x32_bf16(bK, aQ[c], a, 0, 0, 0);
        }
        s[nb] = a;
    }
    __builtin_amdgcn_s_setprio(0);
    // ---- causal mask (diagonal tile only; wave-uniform branch)
    // s[nb][r] is key  kb + (nb&3)*32 + hi*8 + (nb>>2)*4 + r
    if (kb + KVB - 1 > qbase) {
#pragma unroll
        for (int nb = 0; nb < 8; ++nb) {
            int keyb = kb + (nb & 3) * 32 + hi * 8 + (nb >> 2) * 4;
#pragma unroll
            for (int r = 0; r < 4; ++r)
                if (keyb + r > qrow) s[nb][r] = -1e30f;
        }
    }
    // ---- row max: in-lane tree over 32 values + 2 shfl across hi-groups
    float pm = -INFINITY;
#pragma unroll
    for (int nb = 0; nb < 8; ++nb)
        pm = fmaxf(pm, fmaxf(fmaxf(s[nb][0], s[nb][1]), fmaxf(s[nb][2], s[nb][3])));
    pm = fmaxf(pm, __shfl_xor(pm, 16));
    pm = fmaxf(pm, __shfl_xor(pm, 32));
    // ---- defer-max (T13, THR=8): rescale only on growth beyond headroom
    if (__any(pm > st.mrun + 8.0f)) {
        float mnew = fmaxf(st.mrun, pm);
        float sf = exp2f((st.mrun - mnew) * L2E);
        st.mrun = mnew;
        st.lrun *= sf;
#pragma unroll
        for (int dt = 0; dt < 4; ++dt)
#pragma unroll
            for (int r = 0; r < 4; ++r) st.o[dt][r] *= sf;
    }
    float mterm = st.mrun * L2E;
    // ---- P = exp2(s*L2E - mterm) -> bf16 (packed cvt), as PV B-frags
    short8 bp[4];
#pragma unroll
    for (int c = 0; c < 4; ++c)
#pragma unroll
        for (int jj = 0; jj < 8; ++jj) {
            float p = exp2f(fmaf(s[c + (jj >> 2) * 4][jj & 3], L2E, -mterm));
            bp[c][jj] = f2bfs(p);
        }
    // ---- PV swapped: o^T[d][qrow] += V^T-frag * P^T-frag; + ones row-sum
    f32x4 osum = (f32x4){0.f, 0.f, 0.f, 0.f};
    __builtin_amdgcn_s_setprio(1);
#pragma unroll
    for (int dt = 0; dt < 4; ++dt) {
        int d = dt * 16 + rbase;
#pragma unroll
        for (int c = 0; c < 4; ++c) {
            int slot2 = (c * 4 + hi) ^ (d & 7);
            short8 bV = *(const short8*)&lv[d * 128 + slot2 * 8];
            st.o[dt] = __builtin_amdgcn_mfma_f32_16x16x32_bf16(bV, bp[c], st.o[dt], 0, 0, 0);
        }
    }
#pragma unroll
    for (int c = 0; c < 4; ++c)
        osum = __builtin_amdgcn_mfma_f32_16x16x32_bf16(vone, bp[c], osum, 0, 0, 0);
    __builtin_amdgcn_s_setprio(0);
    st.lrun += osum[0];
}

__global__ __launch_bounds__(512, 4) void attn_kernel(const short* __restrict__ q,
                                                      const short* __restrict__ kk,
                                                      const short* __restrict__ vtg,
                                                      float* __restrict__ out) {
    const int tid  = threadIdx.x;
    const int lane = tid & 63;
    const int wid  = tid >> 6;                       // 0..7
    const int lid  = blockIdx.x;                     // 0..511
    const int xcd  = lid & 7;
    const int v    = lid >> 3;                       // 0..63
    const int h4   = v & 3;                          // head rank on this XCD
    const int ps   = (v >> 2) & 7;                   // CU pair-slot
    const int half = v >> 5;                         // 0 = long half (first)
    const int qt   = half ? ps : (15 - ps);          // q-tile of 128 rows
    const int bh   = h4 * 8 + xcd;                   // pinned to XCD
    const int rbase = lane & 15;                     // my q-row within wave tile
    const int hi    = lane >> 4;

    const short* qh = q   + (size_t)bh * SEQ * HDIM;
    const short* kh = kk  + (size_t)bh * SEQ * HDIM;
    const short* vh = vtg + (size_t)bh * HDIM * SEQ;

    __shared__ short lK[2][KVB * 64];
    __shared__ short lV[2][HDIM * KVB];

    short8 vone;
#pragma unroll
    for (int jj = 0; jj < 8; ++jj) vone[jj] = (short)0x3F80;   // bf16 1.0

    const int b = bh >> 4, h = bh & 15;

    const int qbase = qt * 128 + wid * 16;
    const int qrow  = qbase + rbase;

    // Q fragment (B-frag: lane n=rbase holds Q[qrow][k], k = hi*8+j)
    short8 aQ[2];
#pragma unroll
    for (int c = 0; c < 2; ++c)
        aQ[c] = *(const short8*)&qh[(size_t)qrow * HDIM + c * 32 + hi * 8];

    AttnState st;
#pragma unroll
    for (int i = 0; i < 4; ++i) st.o[i] = (f32x4){0.f, 0.f, 0.f, 0.f};
    st.mrun = -INFINITY;
    st.lrun = 0.f;

    const int ktiles = qt + 1;                       // 128-key tiles, keys 0..qt*128+127
    stage_kv(kh, vh, 0, lK[0], lV[0], tid);
#pragma unroll 1
    for (int t = 0; t < ktiles; t += 2) {
        {   // ---- even tile: compute lK[0]/lV[0], stage t+1 -> buf1
            const int kb = t * KVB;
            if (t + 1 < ktiles) {
                stage_kv(kh, vh, kb + KVB, lK[1], lV[1], tid);
                asm volatile("s_waitcnt vmcnt(4)" ::: "memory");
            } else {
                asm volatile("s_waitcnt vmcnt(0)" ::: "memory");
            }
            __builtin_amdgcn_s_barrier();
            __builtin_amdgcn_sched_barrier(0);
            if (kb < qbase + 16)
                compute_tile(lK[0], lV[0], kb, qbase, qrow, rbase, hi, aQ, vone, st);
            __builtin_amdgcn_sched_barrier(0);
            __builtin_amdgcn_s_barrier();
        }
        if (t + 1 < ktiles) {   // ---- odd tile: compute lK[1]/lV[1], stage t+2 -> buf0
            const int kb = (t + 1) * KVB;
            if (t + 2 < ktiles) {
                stage_kv(kh, vh, kb + KVB, lK[0], lV[0], tid);
                asm volatile("s_waitcnt vmcnt(4)" ::: "memory");
            } else {
                asm volatile("s_waitcnt vmcnt(0)" ::: "memory");
            }
            __builtin_amdgcn_s_barrier();
            __builtin_amdgcn_sched_barrier(0);
            if (kb < qbase + 16)
                compute_tile(lK[1], lV[1], kb, qbase, qrow, rbase, hi, aQ, vone, st);
            __builtin_amdgcn_sched_barrier(0);
            __builtin_amdgcn_s_barrier();
        }
    }

    // write out [B,T,H,D] fp32: lane owns row qrow, d = dt*16 + hi*4 + r
    float inv = 1.0f / st.lrun;
#pragma unroll
    for (int dt = 0; dt < 4; ++dt) {
        f32x4 ov;
#pragma unroll
        for (int r = 0; r < 4; ++r) ov[r] = st.o[dt][r] * inv;
        *(f32x4*)&out[((size_t)(b * SEQ + qrow) * NHEAD + h) * HDIM + dt * 16 + hi * 4] = ov;
    }
}

// ---------------------------------------------------------------- launch
extern "C" void kernel_launch(void* const* d_in, const int* in_sizes, int n_in,
                              void* d_out, int out_size, void* d_ws, size_t ws_size,
                              hipStream_t stream) {
    const float* x = (const float*)d_in[0];
    const float* w = (const float*)d_in[1];
    float* out = (float*)d_out;

    char* ws = (char*)d_ws;
    short* xb   = (short*)(ws);                            // 8 MB  [M,K] bf16
    short* wt   = (short*)(ws + (size_t)8  * 1024 * 1024); // 6 MB  [N3,K] bf16
    short* qb   = (short*)(ws + (size_t)14 * 1024 * 1024); // 8 MB  [B,H,T,D] (pre-scaled 0.125)
    short* kbuf = (short*)(ws + (size_t)22 * 1024 * 1024); // 8 MB  [B,H,T,D]
    short* vt   = (short*)(ws + (size_t)30 * 1024 * 1024); // 8 MB  [B,H,D,T]

    cast_x_kernel<<<dim3(MTOT * KDIM / 4 / 256), dim3(256), 0, stream>>>(x, xb, MTOT * KDIM / 4);
    cast_wt_kernel<<<dim3(N3 / 32, KDIM / 32), dim3(256), 0, stream>>>(w, wt);
    qkv_gemm_kernel<<<dim3(768), dim3(256), 0, stream>>>(xb, wt, qb, kbuf, vt);
    attn_kernel<<<dim3(512), dim3(512), 0, stream>>>(qb, kbuf, vt, out);
}